// Round 14
// baseline (61.607 us; speedup 1.0000x reference)
//
#include <hip/hip_runtime.h>
#include <hip/hip_bf16.h>
#include <cstddef>

#define NAGENT 8
#define DIN    128
#define HID    64
#define NACT   16

typedef __attribute__((ext_vector_type(8)))  short bf16x8;
typedef __attribute__((ext_vector_type(4)))  float f32x4;
typedef __attribute__((ext_vector_type(16))) float f32x16;

__device__ __forceinline__ short f2bf(float f) {
    __hip_bfloat16 h = __float2bfloat16(f);      // RNE; pairs pack to v_cvt_pk_bf16_f32
    union { __hip_bfloat16 h; short s; } u; u.h = h;
    return u.s;
}
__device__ __forceinline__ float sigmoid_f(float v) { return 1.0f / (1.0f + __expf(-v)); }
__device__ __forceinline__ float tanh_f(float v) {
    v = fminf(fmaxf(v, -15.0f), 15.0f);
    float e = __expf(2.0f * v);
    return (e - 1.0f) / (e + 1.0f);
}
__device__ __forceinline__ bf16x8 cvt8pair(float4 v0, float4 v1) {
    bf16x8 r;
    r[0] = f2bf(v0.x); r[1] = f2bf(v0.y); r[2] = f2bf(v0.z); r[3] = f2bf(v0.w);
    r[4] = f2bf(v1.x); r[5] = f2bf(v1.y); r[6] = f2bf(v1.z); r[7] = f2bf(v1.w);
    return r;
}

// ---------------- weight fp32 -> bf16 fragment-major packing (32x32 order) --
// Per-agent 66 chunks of 512 shorts (1KB), base a*33792 shorts:
//   fc1 chunks [0,16):  chunk = n*8+i  -> W1[a][n*32+(l&31)][i*16+(l>>5)*8 ..+8]
//   Wih chunks [16,40): ch=(g*2+cb)*4+ks -> Wih[a][g*64+cb*32+(l&31)][ks*16+(l>>5)*8]
//   Whh chunks [40,64): same with Whh
//   W2  chunks [64,66): old 16x16 format: W2[a][l&15][kk*32+(l>>4)*8]
extern "C" __global__ void __launch_bounds__(256)
conv_weights_packed(const float* __restrict__ W1, const float* __restrict__ Wih,
                    const float* __restrict__ Whh, const float* __restrict__ W2,
                    short* __restrict__ ws)
{
    const int a = blockIdx.y;
    const int c = blockIdx.x * 256 + threadIdx.x;
    if (c >= 4224) return;                 // 66 chunks x 64 lanes
    const int lane  = c & 63;
    const int chunk = c >> 6;
    const int l31 = lane & 31, lkk = lane >> 5;
    const float* src;
    if (chunk < 16) {
        int n = chunk >> 3, i = chunk & 7;
        src = W1 + a * 8192 + (n * 32 + l31) * 128 + i * 16 + lkk * 8;
    } else if (chunk < 40) {
        int idx = chunk - 16;
        int g = idx >> 3, cb = (idx >> 2) & 1, ks = idx & 3;
        src = Wih + a * 12288 + (g * 64 + cb * 32 + l31) * 64 + ks * 16 + lkk * 8;
    } else if (chunk < 64) {
        int idx = chunk - 40;
        int g = idx >> 3, cb = (idx >> 2) & 1, ks = idx & 3;
        src = Whh + a * 12288 + (g * 64 + cb * 32 + l31) * 64 + ks * 16 + lkk * 8;
    } else {
        int kk = chunk - 64;
        src = W2 + a * 1024 + (lane & 15) * 64 + kk * 32 + (lane >> 4) * 8;
    }
    float4 v0 = ((const float4*)src)[0];
    float4 v1 = ((const float4*)src)[1];
    bf16x8 o = cvt8pair(v0, v1);
    *(bf16x8*)(ws + (size_t)a * 33792 + (size_t)c * 8) = o;
}

// ---------------- main fused kernel: 32-row waves, 32x32x16 MFMA ------------
// grid 1024 (1-D, agent = bid&7: one agent per CU), 256 threads (4 waves),
// ONE 32-row tile per wave. 32x32x16 MFMA consumes 1KB weight per 16K MACs
// (vs 8K for 16x16x32): per-row weight traffic HALVES (540->270 MB L2 reads),
// the dominant stall source (r10-r13 evidence: time ~ weight stream).
// f32x16 accumulators -> ~120 live VGPRs -> __launch_bounds__(256,2) 128-tier,
// 4 waves/SIMD, 1024 blocks = exactly resident. fc2 (N=16) stays 16x16x32.
// C/D: col=lane&31, row=(reg&3)+8*(reg>>2)+4*(lane>>5) [m74/m101].
extern "C" __global__ void __launch_bounds__(256, 2)
rnn_main(const float* __restrict__ x,     // [B*A, D]
         const float* __restrict__ hin,   // [B, A, H]
         const float* __restrict__ b1, const float* __restrict__ bih,
         const float* __restrict__ bhh, const float* __restrict__ b2,
         const short* __restrict__ wsp,   // packed bf16 weights
         float* __restrict__ qout,        // [B*A, NACT]
         float* __restrict__ hout)        // [B, A, H]
{
    const int bid  = blockIdx.x;
    const int a    = bid & 7;
    const int t    = threadIdx.x;
    const int wid  = t >> 6;              // 0..3
    const int lane = t & 63;
    const int l31  = lane & 31;
    const int lkk  = lane >> 5;

    __shared__ short zs[4 * 2048];        // 4 per-wave 4KB transpose buffers
    char* zb = (char*)(zs + wid * 2048);

    const short* wsA = wsp + (size_t)a * 33792;
    const int rbase = ((bid >> 3) * 4 + wid) * 32;
    const int arow  = rbase + l31;

    const float* xrow = x + ((size_t)arow * NAGENT + a) * DIN + lkk * 8;
    const float* hrow = hin + ((size_t)arow * NAGENT + a) * HID + lkk * 8;

    // h A-frags: row=l31, k = ks*16 + lkk*8
    bf16x8 hf[4];
    #pragma unroll
    for (int ks = 0; ks < 4; ++ks)
        hf[ks] = cvt8pair(*(const float4*)(hrow + ks * 16),
                          *(const float4*)(hrow + ks * 16 + 4));

    // ---- fc1: z1 = relu(x @ W1^T + b1): M=32, N=64 (2 blocks), K=128 ----
    {
        float bv0 = b1[a * HID + l31];
        float bv1 = b1[a * HID + 32 + l31];
        f32x16 acc0, acc1;
        #pragma unroll
        for (int r = 0; r < 16; ++r) { acc0[r] = bv0; acc1[r] = bv1; }
        #pragma unroll
        for (int i = 0; i < 8; ++i) {
            bf16x8 xa = cvt8pair(*(const float4*)(xrow + i * 16),
                                 *(const float4*)(xrow + i * 16 + 4));
            bf16x8 w0 = *(const bf16x8*)(wsA + ((0 * 8 + i) * 64 + lane) * 8);
            bf16x8 w1 = *(const bf16x8*)(wsA + ((1 * 8 + i) * 64 + lane) * 8);
            acc0 = __builtin_amdgcn_mfma_f32_32x32x16_bf16(xa, w0, acc0, 0, 0, 0);
            acc1 = __builtin_amdgcn_mfma_f32_32x32x16_bf16(xa, w1, acc1, 0, 0, 0);
        }
        #pragma unroll
        for (int r = 0; r < 16; ++r) {
            int row = (r & 3) + 8 * (r >> 2) + 4 * lkk;
            int c0 = l31, c1 = 32 + l31;
            *(short*)(zb + row * 128 + ((c0 * 2) ^ ((row & 7) << 4))) =
                f2bf(fmaxf(acc0[r], 0.0f));
            *(short*)(zb + row * 128 + ((c1 * 2) ^ ((row & 7) << 4))) =
                f2bf(fmaxf(acc1[r], 0.0f));
        }
    }

    // ---- z1 back as A-frags: row=l31, k = ks*16 + lkk*8 ----
    bf16x8 za[4];
    #pragma unroll
    for (int ks = 0; ks < 4; ++ks)
        za[ks] = *(const bf16x8*)(zb + l31 * 128 +
                                  ((ks * 32 + lkk * 16) ^ ((l31 & 7) << 4)));

    // ---- GRU gates, 2 col-blocks of 32 ----
    #pragma unroll 1
    for (int cb = 0; cb < 2; ++cb) {
        const int col = cb * 32 + l31;
        f32x16 rv, zv;

        // gate r (g=0)
        {
            float bh = bhh[a * 192 + 0 * 64 + col];
            float bi = bih[a * 192 + 0 * 64 + col];
            f32x16 aH, aI;
            #pragma unroll
            for (int r = 0; r < 16; ++r) { aH[r] = bh; aI[r] = bi; }
            #pragma unroll
            for (int ks = 0; ks < 4; ++ks) {
                bf16x8 wh = *(const bf16x8*)(wsA + ((40 + (0 * 2 + cb) * 4 + ks) * 64 + lane) * 8);
                bf16x8 wi = *(const bf16x8*)(wsA + ((16 + (0 * 2 + cb) * 4 + ks) * 64 + lane) * 8);
                aH = __builtin_amdgcn_mfma_f32_32x32x16_bf16(hf[ks], wh, aH, 0, 0, 0);
                aI = __builtin_amdgcn_mfma_f32_32x32x16_bf16(za[ks], wi, aI, 0, 0, 0);
            }
            #pragma unroll
            for (int r = 0; r < 16; ++r) rv[r] = sigmoid_f(aI[r] + aH[r]);
        }
        // gate z (g=1)
        {
            float bh = bhh[a * 192 + 1 * 64 + col];
            float bi = bih[a * 192 + 1 * 64 + col];
            f32x16 aH, aI;
            #pragma unroll
            for (int r = 0; r < 16; ++r) { aH[r] = bh; aI[r] = bi; }
            #pragma unroll
            for (int ks = 0; ks < 4; ++ks) {
                bf16x8 wh = *(const bf16x8*)(wsA + ((40 + (1 * 2 + cb) * 4 + ks) * 64 + lane) * 8);
                bf16x8 wi = *(const bf16x8*)(wsA + ((16 + (1 * 2 + cb) * 4 + ks) * 64 + lane) * 8);
                aH = __builtin_amdgcn_mfma_f32_32x32x16_bf16(hf[ks], wh, aH, 0, 0, 0);
                aI = __builtin_amdgcn_mfma_f32_32x32x16_bf16(za[ks], wi, aI, 0, 0, 0);
            }
            #pragma unroll
            for (int r = 0; r < 16; ++r) zv[r] = sigmoid_f(aI[r] + aH[r]);
        }
        // gate n (g=2) + elementwise + stores
        {
            float bh = bhh[a * 192 + 2 * 64 + col];
            float bi = bih[a * 192 + 2 * 64 + col];
            f32x16 aH, aI;
            #pragma unroll
            for (int r = 0; r < 16; ++r) { aH[r] = bh; aI[r] = bi; }
            #pragma unroll
            for (int ks = 0; ks < 4; ++ks) {
                bf16x8 wh = *(const bf16x8*)(wsA + ((40 + (2 * 2 + cb) * 4 + ks) * 64 + lane) * 8);
                bf16x8 wi = *(const bf16x8*)(wsA + ((16 + (2 * 2 + cb) * 4 + ks) * 64 + lane) * 8);
                aH = __builtin_amdgcn_mfma_f32_32x32x16_bf16(hf[ks], wh, aH, 0, 0, 0);
                aI = __builtin_amdgcn_mfma_f32_32x32x16_bf16(za[ks], wi, aI, 0, 0, 0);
            }
            #pragma unroll
            for (int r = 0; r < 16; ++r) {
                int row = (r & 3) + 8 * (r >> 2) + 4 * lkk;
                float hp = hin[((size_t)(rbase + row) * NAGENT + a) * HID + col];
                float nn = tanh_f(aI[r] + rv[r] * aH[r]);
                float hv = (1.0f - zv[r]) * nn + zv[r] * hp;
                hout[((size_t)(rbase + row) * NAGENT + a) * HID + col] = hv;
                *(short*)(zb + row * 128 + ((col * 2) ^ ((row & 7) << 4))) = f2bf(hv);
            }
        }
    }

    // ---- fc2: q = h_new @ W2^T + b2 (two 16-row halves, 16x16x32) ----
    {
        const int lr = lane & 15, lk4 = lane >> 4;
        float bq = b2[a * NACT + lr];
        bf16x8 w2f0 = *(const bf16x8*)(wsA + ((64 + 0) * 64 + lane) * 8);
        bf16x8 w2f1 = *(const bf16x8*)(wsA + ((64 + 1) * 64 + lane) * 8);
        #pragma unroll
        for (int h = 0; h < 2; ++h) {
            int zr = h * 16 + lr;
            bf16x8 ha0 = *(const bf16x8*)(zb + zr * 128 +
                          ((0 * 64 + lk4 * 16) ^ ((lr & 7) << 4)));
            bf16x8 ha1 = *(const bf16x8*)(zb + zr * 128 +
                          ((1 * 64 + lk4 * 16) ^ ((lr & 7) << 4)));
            f32x4 q = (f32x4){bq, bq, bq, bq};
            q = __builtin_amdgcn_mfma_f32_16x16x32_bf16(ha0, w2f0, q, 0, 0, 0);
            q = __builtin_amdgcn_mfma_f32_16x16x32_bf16(ha1, w2f1, q, 0, 0, 0);
            #pragma unroll
            for (int j = 0; j < 4; ++j)
                qout[((size_t)(rbase + h * 16 + lk4 * 4 + j) * NAGENT + a) * NACT + lr] = q[j];
        }
    }
}

extern "C" void kernel_launch(void* const* d_in, const int* in_sizes, int n_in,
                              void* d_out, int out_size, void* d_ws, size_t ws_size,
                              hipStream_t stream)
{
    const float* x   = (const float*)d_in[0];
    const float* hin = (const float*)d_in[1];
    const float* W1  = (const float*)d_in[2];
    const float* b1  = (const float*)d_in[3];
    const float* Wih = (const float*)d_in[4];
    const float* bih = (const float*)d_in[5];
    const float* Whh = (const float*)d_in[6];
    const float* bhh = (const float*)d_in[7];
    const float* W2  = (const float*)d_in[8];
    const float* b2  = (const float*)d_in[9];

    const int B = in_sizes[0] / (NAGENT * DIN);   // 16384

    float* qout = (float*)d_out;                              // [B*A, NACT]
    float* hout = (float*)d_out + (size_t)B * NAGENT * NACT;  // [B, A, H]

    short* wsp = (short*)d_ws;                                // 540,672 B packed

    conv_weights_packed<<<dim3(17, NAGENT), 256, 0, stream>>>(W1, Wih, Whh, W2, wsp);

    // 1-D grid: (B/128)*8 = 1024 blocks; agent = bid & 7 (one agent per CU
    // under linear round-robin dispatch since 256 % 8 == 0).
    dim3 grid((B / 128) * NAGENT);
    rnn_main<<<grid, 256, 0, stream>>>(x, hin, b1, bih, bhh, b2, wsp, qout, hout);
}

// Round 15
// 48.708 us; speedup vs baseline: 1.2648x; 1.2648x over previous
//
#include <hip/hip_runtime.h>
#include <hip/hip_bf16.h>
#include <cstddef>

#define NAGENT 8
#define DIN    128
#define HID    64
#define NACT   16

typedef __attribute__((ext_vector_type(8))) short bf16x8;
typedef __attribute__((ext_vector_type(4))) float f32x4;

__device__ __forceinline__ short f2bf(float f) {
    __hip_bfloat16 h = __float2bfloat16(f);      // RNE; pairs pack to v_cvt_pk_bf16_f32
    union { __hip_bfloat16 h; short s; } u; u.h = h;
    return u.s;
}
__device__ __forceinline__ float sigmoid_f(float v) { return 1.0f / (1.0f + __expf(-v)); }
__device__ __forceinline__ float tanh_f(float v) {
    v = fminf(fmaxf(v, -15.0f), 15.0f);
    float e = __expf(2.0f * v);
    return (e - 1.0f) / (e + 1.0f);
}
__device__ __forceinline__ bf16x8 cvt8pair(float4 v0, float4 v1) {
    bf16x8 r;
    r[0] = f2bf(v0.x); r[1] = f2bf(v0.y); r[2] = f2bf(v0.z); r[3] = f2bf(v0.w);
    r[4] = f2bf(v1.x); r[5] = f2bf(v1.y); r[6] = f2bf(v1.z); r[7] = f2bf(v1.w);
    return r;
}
__device__ __forceinline__ void gload_lds16(const void* g, void* l) {
    __builtin_amdgcn_global_load_lds(
        (const __attribute__((address_space(1))) unsigned int*)g,
        (__attribute__((address_space(3))) unsigned int*)l, 16, 0, 0);
}

// ---------------- weight fp32 -> bf16 fragment-major packing ----------------
// Per-agent packed layout (shorts), base a*33792; in 1KB "rounds" (512 shorts):
//   W1  rounds  0..15 : fragment f=(n*4+k)   -> W1[a][n*16+lr][k*32+lk*8]
//   Wih rounds 16..39 : fragment (g*4+n)*2+kk -> Wih[a][g*64+n*16+lr][kk*32+lk*8]
//   Whh rounds 40..63 : same with Whh
//   W2  rounds 64..65 : fragment kk          -> W2[a][lr][kk*32+lk*8]
extern "C" __global__ void __launch_bounds__(256)
conv_weights_packed(const float* __restrict__ W1, const float* __restrict__ Wih,
                    const float* __restrict__ Whh, const float* __restrict__ W2,
                    short* __restrict__ ws)
{
    const int a = blockIdx.y;
    const int c = blockIdx.x * 256 + threadIdx.x;
    if (c >= 4224) return;
    const int lane = c & 63, lr = lane & 15, lk = lane >> 4;
    const float* src;
    if (c < 1024) {
        int n = c >> 8, k = (c >> 6) & 3;
        src = W1 + a * 8192 + (n * 16 + lr) * 128 + k * 32 + lk * 8;
    } else if (c < 2560) {
        int idx = (c - 1024) >> 6;
        int g = idx >> 3, n = (idx >> 1) & 3, kk = idx & 1;
        src = Wih + a * 12288 + (g * 64 + n * 16 + lr) * 64 + kk * 32 + lk * 8;
    } else if (c < 4096) {
        int idx = (c - 2560) >> 6;
        int g = idx >> 3, n = (idx >> 1) & 3, kk = idx & 1;
        src = Whh + a * 12288 + (g * 64 + n * 16 + lr) * 64 + kk * 32 + lk * 8;
    } else {
        int kk = (c - 4096) >> 6;
        src = W2 + a * 1024 + lr * 64 + kk * 32 + lk * 8;
    }
    float4 v0 = ((const float4*)src)[0];
    float4 v1 = ((const float4*)src)[1];
    bf16x8 o = cvt8pair(v0, v1);
    *(bf16x8*)(ws + (size_t)a * 33792 + (size_t)c * 8) = o;
}

// ---------------- main fused kernel ----------------
// r10's lean 64-VGPR-tier body (the r2/r10/r11/r14 law: time tracks resident
// waves; stay at 32 waves/CU) + BLOCK-SHARED LDS WEIGHT STAGING:
//  - 12KB wbuf per block, filled phase-by-phase via global_load_lds (no VGPR
//    cost); 4 waves share -> per-CU weight VMEM ops drop 4x, and col-block
//    weight reads become ~120cy conflict-free ds_read_b128 instead of ~300cy
//    L2 chains.
//  - LDS = 12KB wbuf + 4x2KB transpose = 20480B exactly -> 8 blocks/CU at the
//    64-VGPR tier = 32 waves/CU (unchanged from r10).
//  - Phases: fc1 in 2 halves (8 rounds each), 4 gate col-blocks (12 rounds
//    each, 3 per wave); hp/bias loads issued in the staging-drain windows.
//  - 8 independent blocks/CU (1 wave each per SIMD) give barrier phase
//    diversity.
extern "C" __global__ void __launch_bounds__(256, 4)
rnn_main(const float* __restrict__ x,     // [B*A, D]
         const float* __restrict__ hin,   // [B, A, H]
         const float* __restrict__ b1, const float* __restrict__ bih,
         const float* __restrict__ bhh, const float* __restrict__ b2,
         const short* __restrict__ wsp,   // packed bf16 weights
         float* __restrict__ qout,        // [B*A, NACT]
         float* __restrict__ hout)        // [B, A, H]
{
    const int bid  = blockIdx.x;
    const int a    = bid & 7;             // one agent per CU (r13 layout)
    const int t    = threadIdx.x;
    const int wid  = t >> 6;              // 0..3
    const int lane = t & 63;
    const int lr   = lane & 15;
    const int lk   = lane >> 4;

    __shared__ short wbuf[6144];          // 12 KB shared weight staging
    __shared__ short zs[4 * 1024];        // 4 per-wave 2KB transpose buffers
    char* zb = (char*)(zs + wid * 1024);

    const short* wsA = wsp + (size_t)a * 33792;
    const int tile = (bid >> 3) * 4 + wid;
    const int arow = tile * 16 + lr;

    const float* xrow = x + ((size_t)arow * NAGENT + a) * DIN + lk * 8;
    const float* hrow = hin + ((size_t)arow * NAGENT + a) * HID + lk * 8;

    // ---- stage fc1 half 0 (rounds 0..7; 2 rounds per wave) ----
    gload_lds16(wsA + (size_t)(wid * 2 + 0) * 512 + lane * 8, wbuf + (wid * 2 + 0) * 512);
    gload_lds16(wsA + (size_t)(wid * 2 + 1) * 512 + lane * 8, wbuf + (wid * 2 + 1) * 512);

    // x/h fragments (global loads overlap staging drain)
    bf16x8 xf[4];
    #pragma unroll
    for (int k = 0; k < 4; ++k)
        xf[k] = cvt8pair(*(const float4*)(xrow + k * 32),
                         *(const float4*)(xrow + k * 32 + 4));
    bf16x8 hf0 = cvt8pair(*(const float4*)(hrow),      *(const float4*)(hrow + 4));
    bf16x8 hf1 = cvt8pair(*(const float4*)(hrow + 32), *(const float4*)(hrow + 36));

    f32x4 acc1[4];
    #pragma unroll
    for (int n = 0; n < 4; ++n) {
        float bv = b1[a * HID + n * 16 + lr];
        acc1[n] = (f32x4){bv, bv, bv, bv};
    }

    __syncthreads();                      // wbuf[fc1.0] ready

    // ---- fc1 half 0: n in {0,1} ----
    #pragma unroll
    for (int k = 0; k < 4; ++k)
        #pragma unroll
        for (int n = 0; n < 2; ++n) {
            bf16x8 wb = *(const bf16x8*)(wbuf + ((n * 4 + k) * 64 + lane) * 8);
            acc1[n] = __builtin_amdgcn_mfma_f32_16x16x32_bf16(xf[k], wb, acc1[n], 0, 0, 0);
        }
    __syncthreads();                      // all reads of wbuf[fc1.0] done

    // ---- stage fc1 half 1 (rounds 8..15) ----
    gload_lds16(wsA + (size_t)(8 + wid * 2 + 0) * 512 + lane * 8, wbuf + (wid * 2 + 0) * 512);
    gload_lds16(wsA + (size_t)(8 + wid * 2 + 1) * 512 + lane * 8, wbuf + (wid * 2 + 1) * 512);
    __syncthreads();                      // wbuf[fc1.1] ready

    // ---- fc1 half 1: n in {2,3}; then z1 -> LDS ----
    #pragma unroll
    for (int k = 0; k < 4; ++k)
        #pragma unroll
        for (int n = 2; n < 4; ++n) {
            bf16x8 wb = *(const bf16x8*)(wbuf + (((n * 4 + k) - 8) * 64 + lane) * 8);
            acc1[n] = __builtin_amdgcn_mfma_f32_16x16x32_bf16(xf[k], wb, acc1[n], 0, 0, 0);
        }
    #pragma unroll
    for (int n = 0; n < 4; ++n)
        #pragma unroll
        for (int j = 0; j < 4; ++j) {
            int row = lk * 4 + j, col = n * 16 + lr;
            *(short*)(zb + row * 128 + ((col * 2) ^ ((row & 7) << 4))) =
                f2bf(fmaxf(acc1[n][j], 0.0f));
        }

    // ---- z1 back as A-fragments ----
    bf16x8 za0 = *(const bf16x8*)(zb + lr * 128 + ((0 * 64 + lk * 16) ^ ((lr & 7) << 4)));
    bf16x8 za1 = *(const bf16x8*)(zb + lr * 128 + ((1 * 64 + lk * 16) ^ ((lr & 7) << 4)));

    // ---- GRU gates, col-block-wise; weights block-staged per col-block ----
    // wbuf slots: s = g*2+kk (i-path, rounds 16+(g*4+n)*2+kk),
    //             s = 6+g*2+kk (h-path, rounds 40+(g*4+n)*2+kk)
    #pragma unroll 1
    for (int n = 0; n < 4; ++n) {
        __syncthreads();                  // prior-phase wbuf reads complete
        #pragma unroll
        for (int si = 0; si < 3; ++si) {
            int s = wid + si * 4;
            int round = (s < 6) ? (16 + ((s >> 1) * 4 + n) * 2 + (s & 1))
                                : (40 + (((s - 6) >> 1) * 4 + n) * 2 + ((s - 6) & 1));
            gload_lds16(wsA + (size_t)round * 512 + lane * 8, wbuf + s * 512);
        }
        // prefetch hp + biases during staging drain
        float hp[4];
        #pragma unroll
        for (int j = 0; j < 4; ++j)
            hp[j] = hin[((size_t)(tile * 16 + lk * 4 + j) * NAGENT + a) * HID + n * 16 + lr];
        float bhr = bhh[a * 192 +   0 + n * 16 + lr];
        float bhz = bhh[a * 192 +  64 + n * 16 + lr];
        float bhn = bhh[a * 192 + 128 + n * 16 + lr];
        float bir = bih[a * 192 +   0 + n * 16 + lr];
        float biz = bih[a * 192 +  64 + n * 16 + lr];
        float bin_ = bih[a * 192 + 128 + n * 16 + lr];
        __syncthreads();                  // wbuf[gates n] ready

        f32x4 aHr = (f32x4){bhr, bhr, bhr, bhr};
        f32x4 aHz = (f32x4){bhz, bhz, bhz, bhz};
        f32x4 aHn = (f32x4){bhn, bhn, bhn, bhn};
        f32x4 aIr = (f32x4){bir, bir, bir, bir};
        f32x4 aIz = (f32x4){biz, biz, biz, biz};
        f32x4 aIn = (f32x4){bin_, bin_, bin_, bin_};
        #pragma unroll
        for (int kk = 0; kk < 2; ++kk) {
            bf16x8 hfk = kk ? hf1 : hf0;
            bf16x8 zak = kk ? za1 : za0;
            bf16x8 wir = *(const bf16x8*)(wbuf + ((0 * 2 + kk) * 64 + lane) * 8);
            bf16x8 wiz = *(const bf16x8*)(wbuf + ((1 * 2 + kk) * 64 + lane) * 8);
            bf16x8 win = *(const bf16x8*)(wbuf + ((2 * 2 + kk) * 64 + lane) * 8);
            bf16x8 whr = *(const bf16x8*)(wbuf + ((6 + 0 * 2 + kk) * 64 + lane) * 8);
            bf16x8 whz = *(const bf16x8*)(wbuf + ((6 + 1 * 2 + kk) * 64 + lane) * 8);
            bf16x8 whn = *(const bf16x8*)(wbuf + ((6 + 2 * 2 + kk) * 64 + lane) * 8);
            aHr = __builtin_amdgcn_mfma_f32_16x16x32_bf16(hfk, whr, aHr, 0, 0, 0);
            aHz = __builtin_amdgcn_mfma_f32_16x16x32_bf16(hfk, whz, aHz, 0, 0, 0);
            aHn = __builtin_amdgcn_mfma_f32_16x16x32_bf16(hfk, whn, aHn, 0, 0, 0);
            aIr = __builtin_amdgcn_mfma_f32_16x16x32_bf16(zak, wir, aIr, 0, 0, 0);
            aIz = __builtin_amdgcn_mfma_f32_16x16x32_bf16(zak, wiz, aIz, 0, 0, 0);
            aIn = __builtin_amdgcn_mfma_f32_16x16x32_bf16(zak, win, aIn, 0, 0, 0);
        }

        // elementwise + stores for this col-block
        #pragma unroll
        for (int j = 0; j < 4; ++j) {
            int row = lk * 4 + j, col = n * 16 + lr;
            float r  = sigmoid_f(aIr[j] + aHr[j]);
            float zv = sigmoid_f(aIz[j] + aHz[j]);
            float nn = tanh_f(aIn[j] + r * aHn[j]);
            float hv = (1.0f - zv) * nn + zv * hp[j];
            hout[((size_t)(tile * 16 + row) * NAGENT + a) * HID + col] = hv;
            *(short*)(zb + row * 128 + ((col * 2) ^ ((row & 7) << 4))) = f2bf(hv);
        }
    }

    // ---- fc2: q = h_new @ W2^T + b2 (W2 streamed from L2, 2 loads) ----
    {
        float bq = b2[a * NACT + lr];
        f32x4 q = (f32x4){bq, bq, bq, bq};
        bf16x8 ha0 = *(const bf16x8*)(zb + lr * 128 + ((0 * 64 + lk * 16) ^ ((lr & 7) << 4)));
        bf16x8 ha1 = *(const bf16x8*)(zb + lr * 128 + ((1 * 64 + lk * 16) ^ ((lr & 7) << 4)));
        bf16x8 w2f0 = *(const bf16x8*)(wsA + 32768 + (0 * 64 + lane) * 8);
        bf16x8 w2f1 = *(const bf16x8*)(wsA + 32768 + (1 * 64 + lane) * 8);
        q = __builtin_amdgcn_mfma_f32_16x16x32_bf16(ha0, w2f0, q, 0, 0, 0);
        q = __builtin_amdgcn_mfma_f32_16x16x32_bf16(ha1, w2f1, q, 0, 0, 0);
        #pragma unroll
        for (int j = 0; j < 4; ++j)
            qout[((size_t)(tile * 16 + lk * 4 + j) * NAGENT + a) * NACT + lr] = q[j];
    }
}

extern "C" void kernel_launch(void* const* d_in, const int* in_sizes, int n_in,
                              void* d_out, int out_size, void* d_ws, size_t ws_size,
                              hipStream_t stream)
{
    const float* x   = (const float*)d_in[0];
    const float* hin = (const float*)d_in[1];
    const float* W1  = (const float*)d_in[2];
    const float* b1  = (const float*)d_in[3];
    const float* Wih = (const float*)d_in[4];
    const float* bih = (const float*)d_in[5];
    const float* Whh = (const float*)d_in[6];
    const float* bhh = (const float*)d_in[7];
    const float* W2  = (const float*)d_in[8];
    const float* b2  = (const float*)d_in[9];

    const int B = in_sizes[0] / (NAGENT * DIN);   // 16384

    float* qout = (float*)d_out;                              // [B*A, NACT]
    float* hout = (float*)d_out + (size_t)B * NAGENT * NACT;  // [B, A, H]

    short* wsp = (short*)d_ws;                                // 540,672 B packed

    conv_weights_packed<<<dim3(17, NAGENT), 256, 0, stream>>>(W1, Wih, Whh, W2, wsp);

    // 1-D grid: 2048 blocks; agent = bid & 7 (one agent per CU under linear
    // round-robin dispatch since 256 % 8 == 0).
    dim3 grid((B / 64) * NAGENT);
    rnn_main<<<grid, 256, 0, stream>>>(x, hin, b1, bih, bhh, b2, wsp, qout, hout);
}